// Round 1
// baseline (257.742 us; speedup 1.0000x reference)
//
#include <hip/hip_runtime.h>
#include <hip/hip_bf16.h>
#include <stdint.h>

#define B_ 4
#define S_ 2048
#define D_ 1024

typedef __attribute__((ext_vector_type(8))) short short8;
typedef __attribute__((ext_vector_type(4))) float f32x4;

__device__ inline ushort f2bf(float f) {
  union { float f; uint32_t u; } v; v.f = f;
  uint32_t u = v.u;
  u += 0x7FFFu + ((u >> 16) & 1u);   // round-to-nearest-even
  return (ushort)(u >> 16);
}

__device__ inline void gload_lds16(const ushort* g, ushort* l) {
  __builtin_amdgcn_global_load_lds(
      (__attribute__((address_space(1))) void*)(uintptr_t)g,
      (__attribute__((address_space(3))) void*)(uintptr_t)l,
      16, 0, 0);
}

// ---------------- fp32 -> bf16 convert ----------------
__global__ __launch_bounds__(256) void convert_f32_bf16(
    const float* __restrict__ in, ushort* __restrict__ out, int n) {
  int i = (blockIdx.x * 256 + threadIdx.x) * 4;
  if (i >= n) return;
  float4 f = *(const float4*)(in + i);
  ushort4 o;
  o.x = f2bf(f.x); o.y = f2bf(f.y); o.z = f2bf(f.z); o.w = f2bf(f.w);
  *(ushort4*)(out + i) = o;
}

// ---------------- NT GEMM: C[m][n] = scale * sum_k A[m][k]*B[n][k] ----------
// A: [M][K] bf16 row-major, B: [N][K] bf16 row-major. 128x128 tile, BK=32,
// 4 waves in 2x2, each wave 64x64 (4x4 frags of 16x16x32 MFMA).
template <bool OUT_BF16>
__global__ __launch_bounds__(256) void gemm_nt(
    const ushort* __restrict__ A, const ushort* __restrict__ Bm,
    void* __restrict__ C, int M, int N, int K,
    long strideA, long strideB, long strideC, float scale) {
  __shared__ ushort As[128 * 32];
  __shared__ ushort Bs[128 * 32];
  const int tid = threadIdx.x;
  const int wid = tid >> 6, lane = tid & 63;
  const int wr = wid >> 1, wc = wid & 1;
  const int m0 = blockIdx.x * 128;
  const int n0 = blockIdx.y * 128;
  const ushort* Ab = A + (size_t)blockIdx.z * strideA;
  const ushort* Bb = Bm + (size_t)blockIdx.z * strideB;
  const int la = lane & 15;        // frag row/col
  const int kg = lane >> 4;        // k-group (0..3)

  f32x4 acc[4][4];
  #pragma unroll
  for (int i = 0; i < 4; ++i)
    #pragma unroll
    for (int j = 0; j < 4; ++j) acc[i][j] = (f32x4)(0.f);

  for (int k0 = 0; k0 < K; k0 += 32) {
    #pragma unroll
    for (int it = 0; it < 2; ++it) {
      int c = tid + it * 256;          // chunk id 0..511
      int row = c >> 2;                // 4 chunks (32 elems) per row
      int ko = (c & 3) * 8;
      gload_lds16(Ab + (size_t)(m0 + row) * K + k0 + ko, &As[c * 8]);
      gload_lds16(Bb + (size_t)(n0 + row) * K + k0 + ko, &Bs[c * 8]);
    }
    __syncthreads();
    short8 af[4], bf[4];
    #pragma unroll
    for (int i = 0; i < 4; ++i) {
      af[i] = *(const short8*)&As[(wr * 64 + i * 16 + la) * 32 + kg * 8];
      bf[i] = *(const short8*)&Bs[(wc * 64 + i * 16 + la) * 32 + kg * 8];
    }
    #pragma unroll
    for (int i = 0; i < 4; ++i)
      #pragma unroll
      for (int j = 0; j < 4; ++j)
        acc[i][j] = __builtin_amdgcn_mfma_f32_16x16x32_bf16(af[i], bf[j], acc[i][j], 0, 0, 0);
    __syncthreads();
  }

  // epilogue: C/D layout col=lane&15, row=(lane>>4)*4+jj
  char* Cb = (char*)C;
  #pragma unroll
  for (int i = 0; i < 4; ++i) {
    #pragma unroll
    for (int j = 0; j < 4; ++j) {
      int r = m0 + wr * 64 + i * 16 + kg * 4;
      int col = n0 + wc * 64 + j * 16 + la;
      #pragma unroll
      for (int jj = 0; jj < 4; ++jj) {
        float v = acc[i][j][jj] * scale;
        size_t idx = (size_t)blockIdx.z * strideC + (size_t)(r + jj) * N + col;
        if (OUT_BF16) ((ushort*)Cb)[idx] = f2bf(v);
        else          ((float*)Cb)[idx]  = v;
      }
    }
  }
}

// ---------------- transpose V[b][s][e] -> Vt[b][e][s] ----------------
__global__ void transpose_bf16(const ushort* __restrict__ in, ushort* __restrict__ out) {
  __shared__ ushort tile[32][33];
  int b = blockIdx.z;
  const ushort* src = in + (size_t)b * S_ * D_;
  ushort* dst = out + (size_t)b * S_ * D_;
  int r0 = blockIdx.y * 32;   // S
  int c0 = blockIdx.x * 32;   // D
  int tx = threadIdx.x, ty = threadIdx.y;  // 32 x 8
  #pragma unroll
  for (int i = 0; i < 32; i += 8)
    tile[ty + i][tx] = src[(size_t)(r0 + ty + i) * D_ + c0 + tx];
  __syncthreads();
  #pragma unroll
  for (int i = 0; i < 32; i += 8)
    dst[(size_t)(c0 + ty + i) * S_ + r0 + tx] = tile[tx][ty + i];
}

// ---------------- row softmax: fp32 scores -> bf16 probs ----------------
__global__ __launch_bounds__(256) void softmax_rows(
    const float* __restrict__ Sc, ushort* __restrict__ P) {
  size_t row = blockIdx.x;
  const float* src = Sc + row * S_;
  ushort* dst = P + row * S_;
  int tid = threadIdx.x;
  float vals[8];
  float m = -1e30f;
  #pragma unroll
  for (int i = 0; i < 8; ++i) {
    vals[i] = src[tid + i * 256];
    m = fmaxf(m, vals[i]);
  }
  #pragma unroll
  for (int off = 1; off < 64; off <<= 1) m = fmaxf(m, __shfl_xor(m, off));
  __shared__ float redm[4];
  if ((tid & 63) == 0) redm[tid >> 6] = m;
  __syncthreads();
  m = fmaxf(fmaxf(redm[0], redm[1]), fmaxf(redm[2], redm[3]));
  float s = 0.f;
  #pragma unroll
  for (int i = 0; i < 8; ++i) {
    vals[i] = __expf(vals[i] - m);
    s += vals[i];
  }
  #pragma unroll
  for (int off = 1; off < 64; off <<= 1) s += __shfl_xor(s, off);
  __shared__ float reds[4];
  if ((tid & 63) == 0) reds[tid >> 6] = s;
  __syncthreads();
  s = reds[0] + reds[1] + reds[2] + reds[3];
  float inv = 1.0f / s;
  #pragma unroll
  for (int i = 0; i < 8; ++i) dst[tid + i * 256] = f2bf(vals[i] * inv);
}

extern "C" void kernel_launch(void* const* d_in, const int* in_sizes, int n_in,
                              void* d_out, int out_size, void* d_ws, size_t ws_size,
                              hipStream_t stream) {
  const float* x  = (const float*)d_in[0];
  const float* Wq = (const float*)d_in[1];
  const float* Wk = (const float*)d_in[2];
  const float* Wv = (const float*)d_in[3];
  float* out = (float*)d_out;

  char* ws = (char*)d_ws;
  ushort* Xb  = (ushort*)(ws + 0);               // 8192x1024
  ushort* Wqb = (ushort*)(ws + 16777216);        // 1024x1024
  ushort* Wkb = (ushort*)(ws + 18874368);
  ushort* Wvb = (ushort*)(ws + 20971520);
  ushort* Qb  = (ushort*)(ws + 23068672);        // 8192x1024
  ushort* Kb  = (ushort*)(ws + 39845888);
  ushort* Vb  = (ushort*)(ws + 56623104);
  ushort* Vt  = (ushort*)(ws + 73400320);        // [b][1024][2048]
  float*  Sc  = (float*) (ws + 90177536);        // [b][2048][2048] fp32
  ushort* P   = (ushort*)(ws + 157286400);       // [b][2048][2048] bf16

  const int NX = B_ * S_ * D_;   // 8388608
  const int NW = D_ * D_;        // 1048576

  convert_f32_bf16<<<NX / 4 / 256, 256, 0, stream>>>(x, Xb, NX);
  convert_f32_bf16<<<NW / 4 / 256, 256, 0, stream>>>(Wq, Wqb, NW);
  convert_f32_bf16<<<NW / 4 / 256, 256, 0, stream>>>(Wk, Wkb, NW);
  convert_f32_bf16<<<NW / 4 / 256, 256, 0, stream>>>(Wv, Wvb, NW);

  // projections: M=8192, N=1024, K=1024
  {
    dim3 g(8192 / 128, 1024 / 128, 1);
    gemm_nt<true><<<g, 256, 0, stream>>>(Xb, Wqb, Qb, 8192, 1024, 1024, 0, 0, 0, 1.0f);
    gemm_nt<true><<<g, 256, 0, stream>>>(Xb, Wkb, Kb, 8192, 1024, 1024, 0, 0, 0, 1.0f);
    gemm_nt<true><<<g, 256, 0, stream>>>(Xb, Wvb, Vb, 8192, 1024, 1024, 0, 0, 0, 1.0f);
  }

  transpose_bf16<<<dim3(D_ / 32, S_ / 32, B_), dim3(32, 8), 0, stream>>>(Vb, Vt);

  // scores: per batch M=N=2048, K=1024, scale=1/32
  {
    dim3 g(2048 / 128, 2048 / 128, B_);
    gemm_nt<false><<<g, 256, 0, stream>>>(Qb, Kb, Sc, 2048, 2048, 1024,
                                          (long)S_ * D_, (long)S_ * D_, (long)S_ * S_,
                                          1.0f / 32.0f);
  }

  softmax_rows<<<B_ * S_, 256, 0, stream>>>(Sc, P);

  // out = P @ Vt^T: per batch M=2048, N=1024, K=2048
  {
    dim3 g(2048 / 128, 1024 / 128, B_);
    gemm_nt<false><<<g, 256, 0, stream>>>(P, Vt, out, 2048, 1024, 2048,
                                          (long)S_ * S_, (long)S_ * D_, (long)S_ * D_,
                                          1.0f);
  }
}

// Round 2
// 208.230 us; speedup vs baseline: 1.2378x; 1.2378x over previous
//
#include <hip/hip_runtime.h>
#include <stdint.h>

#define B_ 4
#define S_ 2048
#define D_ 1024

typedef __attribute__((ext_vector_type(8))) short short8;
typedef __attribute__((ext_vector_type(4))) float f32x4;

__device__ inline ushort f2bf(float f) {
  union { float f; uint32_t u; } v; v.f = f;
  uint32_t u = v.u;
  u += 0x7FFFu + ((u >> 16) & 1u);   // RNE
  return (ushort)(u >> 16);
}

__device__ inline void gload_lds16(const ushort* g, ushort* l) {
  __builtin_amdgcn_global_load_lds(
      (__attribute__((address_space(1))) void*)(uintptr_t)g,
      (__attribute__((address_space(3))) void*)(uintptr_t)l,
      16, 0, 0);
}

__device__ inline void vwait(int n) {
  switch (n) {
    case 0:  asm volatile("s_waitcnt vmcnt(0)" ::: "memory"); break;
    case 3:  asm volatile("s_waitcnt vmcnt(3)" ::: "memory"); break;
    case 4:  asm volatile("s_waitcnt vmcnt(4)" ::: "memory"); break;
    case 6:  asm volatile("s_waitcnt vmcnt(6)" ::: "memory"); break;
    case 8:  asm volatile("s_waitcnt vmcnt(8)" ::: "memory"); break;
    case 9:  asm volatile("s_waitcnt vmcnt(9)" ::: "memory"); break;
    default: asm volatile("s_waitcnt vmcnt(12)" ::: "memory"); break;
  }
  __builtin_amdgcn_sched_barrier(0);
}

// ---------------- fp32 -> bf16 convert ----------------
__global__ __launch_bounds__(256) void convert_f32_bf16(
    const float* __restrict__ in, ushort* __restrict__ out, int n) {
  int i = (blockIdx.x * 256 + threadIdx.x) * 4;
  if (i >= n) return;
  float4 f = *(const float4*)(in + i);
  ushort4 o;
  o.x = f2bf(f.x); o.y = f2bf(f.y); o.z = f2bf(f.z); o.w = f2bf(f.w);
  *(ushort4*)(out + i) = o;
}

// ------------- deep-pipelined NT GEMM (ring-4 LDS, counted vmcnt) ----------
// C[m][n] = scale * sum_k A[m][k]*B[n][k]; A:[M][lda], B:[N][ldb] bf16.
// BK=32. 512 threads = 8 waves in WM x WN grid; per-wave MF x NF frags 16x16.
// LDS swizzle: LDS[row][c] holds G[row][c ^ ((row>>1)&3)] (16B chunks) --
// source-preswizzled (gload_lds writes linearly), reads XOR the same term.
template <int MF, int NF, int WM, int WN, bool OUT_BF16>
__global__ __launch_bounds__(512) void gemm_pipe(
    const ushort* __restrict__ A, const ushort* __restrict__ Bm,
    void* __restrict__ C, int N, int K, int lda, int ldb, int ldc,
    long sA, long sB, long sC, float scale) {
  constexpr int BM = WM * MF * 16;
  constexpr int BN = WN * NF * 16;
  constexpr int LA = BM / 128;       // gloads/thread for A tile (BM*32 elems)
  constexpr int LB = BN / 128;
  constexpr int L  = LA + LB;
  __shared__ ushort lds[4 * BM * 32 + 4 * BN * 32];
  ushort* ldsA = lds;
  ushort* ldsB = lds + 4 * BM * 32;

  const int tid = threadIdx.x;
  const int wid = tid >> 6, lane = tid & 63;
  const int wr = wid / WN, wc = wid % WN;
  const int la = lane & 15, kg = lane >> 4;
  const int m0 = blockIdx.x * BM, n0 = blockIdx.y * BN;
  const ushort* Ag = A + (size_t)blockIdx.z * sA;
  const ushort* Bg = Bm + (size_t)blockIdx.z * sB;

  // per-thread stage sources (pre-swizzled) and LDS dest offsets (linear)
  const ushort* gA[LA]; int dA[LA];
  #pragma unroll
  for (int i = 0; i < LA; ++i) {
    int ch = tid + i * 512;          // chunk: row = ch>>2, c = ch&3
    int row = ch >> 2, c = ch & 3;
    int cs = c ^ ((row >> 1) & 3);
    gA[i] = Ag + (size_t)(m0 + row) * lda + cs * 8;
    dA[i] = ch * 8;
  }
  const ushort* gB[LB]; int dB[LB];
  #pragma unroll
  for (int i = 0; i < LB; ++i) {
    int ch = tid + i * 512;
    int row = ch >> 2, c = ch & 3;
    int cs = c ^ ((row >> 1) & 3);
    gB[i] = Bg + (size_t)(n0 + row) * ldb + cs * 8;
    dB[i] = ch * 8;
  }

  auto STAGE = [&](int slot) {
    #pragma unroll
    for (int i = 0; i < LA; ++i) {
      gload_lds16(gA[i], ldsA + slot * BM * 32 + dA[i]);
      gA[i] += 32;
    }
    #pragma unroll
    for (int i = 0; i < LB; ++i) {
      gload_lds16(gB[i], ldsB + slot * BN * 32 + dB[i]);
      gB[i] += 32;
    }
  };

  f32x4 acc[MF][NF];
  #pragma unroll
  for (int m = 0; m < MF; ++m)
    #pragma unroll
    for (int n = 0; n < NF; ++n) acc[m][n] = (f32x4)(0.f);

  const int NT = K / 32;
  const int sw = (la >> 1) & 3;
  const int kcol = (kg ^ sw) * 8;
  const int rA = wr * (MF * 16) + la;
  const int rB = wc * (NF * 16) + la;

  STAGE(0); STAGE(1); STAGE(2);      // prologue: tiles 0..2 in flight

  for (int t = 0; t < NT; ++t) {
    if (t + 3 < NT) STAGE((t + 3) & 3);
    int nst = NT - 1 - t;            // future tiles with stages issued
    vwait((nst >= 3 ? 3 : nst) * L); // tile t complete (symmetric wait)
    __builtin_amdgcn_s_barrier();    // all waves agree slot t&3 is ready
    const ushort* sa = ldsA + (t & 3) * BM * 32;
    const ushort* sb = ldsB + (t & 3) * BN * 32;
    short8 af[MF], bf[NF];
    #pragma unroll
    for (int m = 0; m < MF; ++m)
      af[m] = *(const short8*)&sa[(rA + m * 16) * 32 + kcol];
    #pragma unroll
    for (int n = 0; n < NF; ++n)
      bf[n] = *(const short8*)&sb[(rB + n * 16) * 32 + kcol];
    __builtin_amdgcn_s_setprio(1);
    #pragma unroll
    for (int m = 0; m < MF; ++m)
      #pragma unroll
      for (int n = 0; n < NF; ++n)
        acc[m][n] = __builtin_amdgcn_mfma_f32_16x16x32_bf16(af[m], bf[n], acc[m][n], 0, 0, 0);
    __builtin_amdgcn_s_setprio(0);
    __builtin_amdgcn_s_barrier();    // reads of slot t&3 done before it is restaged
  }

  char* Cb = (char*)C;
  #pragma unroll
  for (int m = 0; m < MF; ++m) {
    #pragma unroll
    for (int n = 0; n < NF; ++n) {
      int r = m0 + wr * (MF * 16) + m * 16 + kg * 4;
      int col = n0 + wc * (NF * 16) + n * 16 + la;
      #pragma unroll
      for (int jj = 0; jj < 4; ++jj) {
        float v = acc[m][n][jj] * scale;
        size_t idx = (size_t)blockIdx.z * sC + (size_t)(r + jj) * ldc + col;
        if (OUT_BF16) ((ushort*)Cb)[idx] = f2bf(v);
        else          ((float*)Cb)[idx]  = v;
      }
    }
  }
}

// ---------------- transpose V view [s][e] (ld 3072) -> Vt[b][e][s] ---------
__global__ void transpose_bf16(const ushort* __restrict__ qkv, ushort* __restrict__ out) {
  __shared__ ushort tile[32][33];
  int b = blockIdx.z;
  const ushort* src = qkv + (size_t)b * S_ * 3072 + 2048;  // V columns
  ushort* dst = out + (size_t)b * S_ * D_;
  int r0 = blockIdx.y * 32;   // S
  int c0 = blockIdx.x * 32;   // D
  int tx = threadIdx.x, ty = threadIdx.y;  // 32 x 8
  #pragma unroll
  for (int i = 0; i < 32; i += 8)
    tile[ty + i][tx] = src[(size_t)(r0 + ty + i) * 3072 + c0 + tx];
  __syncthreads();
  #pragma unroll
  for (int i = 0; i < 32; i += 8)
    dst[(size_t)(c0 + ty + i) * S_ + r0 + tx] = tile[tx][ty + i];
}

// ---------------- row softmax: fp32 scores -> bf16 probs ----------------
__global__ __launch_bounds__(256) void softmax_rows(
    const float* __restrict__ Sc, ushort* __restrict__ P) {
  size_t row = blockIdx.x;
  const float* src = Sc + row * S_;
  ushort* dst = P + row * S_;
  int tid = threadIdx.x;
  float vals[8];
  float m = -1e30f;
  #pragma unroll
  for (int i = 0; i < 8; ++i) {
    vals[i] = src[tid + i * 256];
    m = fmaxf(m, vals[i]);
  }
  #pragma unroll
  for (int off = 1; off < 64; off <<= 1) m = fmaxf(m, __shfl_xor(m, off));
  __shared__ float redm[4];
  if ((tid & 63) == 0) redm[tid >> 6] = m;
  __syncthreads();
  m = fmaxf(fmaxf(redm[0], redm[1]), fmaxf(redm[2], redm[3]));
  float s = 0.f;
  #pragma unroll
  for (int i = 0; i < 8; ++i) {
    vals[i] = __expf(vals[i] - m);
    s += vals[i];
  }
  #pragma unroll
  for (int off = 1; off < 64; off <<= 1) s += __shfl_xor(s, off);
  __shared__ float reds[4];
  if ((tid & 63) == 0) reds[tid >> 6] = s;
  __syncthreads();
  s = reds[0] + reds[1] + reds[2] + reds[3];
  float inv = 1.0f / s;
  #pragma unroll
  for (int i = 0; i < 8; ++i) dst[tid + i * 256] = f2bf(vals[i] * inv);
}

extern "C" void kernel_launch(void* const* d_in, const int* in_sizes, int n_in,
                              void* d_out, int out_size, void* d_ws, size_t ws_size,
                              hipStream_t stream) {
  const float* x  = (const float*)d_in[0];
  const float* Wq = (const float*)d_in[1];
  const float* Wk = (const float*)d_in[2];
  const float* Wv = (const float*)d_in[3];
  float* out = (float*)d_out;

  char* ws = (char*)d_ws;
  ushort* Xb   = (ushort*)(ws + 0);               // [8192][1024]
  ushort* Wcat = (ushort*)(ws + 16777216);        // [3072][1024]
  ushort* QKV  = (ushort*)(ws + 23068672);        // [8192][3072]
  ushort* Vt   = (ushort*)(ws + 73400320);        // [b][1024][2048]
  float*  Sc   = (float*) (ws + 90177536);        // [b][2048][2048] fp32
  ushort* P    = (ushort*)(ws + 157286400);       // [b][2048][2048] bf16

  const int NX = B_ * S_ * D_;   // 8388608
  const int NW = D_ * D_;        // 1048576

  convert_f32_bf16<<<NX / 4 / 256, 256, 0, stream>>>(x, Xb, NX);
  convert_f32_bf16<<<NW / 4 / 256, 256, 0, stream>>>(Wq, Wcat, NW);
  convert_f32_bf16<<<NW / 4 / 256, 256, 0, stream>>>(Wk, Wcat + (size_t)D_ * D_, NW);
  convert_f32_bf16<<<NW / 4 / 256, 256, 0, stream>>>(Wv, Wcat + (size_t)2 * D_ * D_, NW);

  // fused QKV projection: M=8192, N=3072, K=1024  (cfgB 256x128, grid 32x24)
  gemm_pipe<4, 4, 4, 2, true><<<dim3(32, 24, 1), 512, 0, stream>>>(
      Xb, Wcat, QKV, 3072, 1024, 1024, 1024, 3072, 0, 0, 0, 1.0f);

  transpose_bf16<<<dim3(D_ / 32, S_ / 32, B_), dim3(32, 8), 0, stream>>>(QKV, Vt);

  // scores: per batch M=N=2048, K=1024  (cfgA 256x256, grid 8x8x4)
  gemm_pipe<8, 4, 2, 4, false><<<dim3(8, 8, B_), 512, 0, stream>>>(
      QKV, QKV + 1024, Sc, 2048, 1024, 3072, 3072, 2048,
      (long)S_ * 3072, (long)S_ * 3072, (long)S_ * S_, 1.0f / 32.0f);

  softmax_rows<<<B_ * S_, 256, 0, stream>>>(Sc, P);

  // out = P @ Vt^T: per batch M=2048, N=1024, K=2048  (cfgB, grid 8x8x4)
  gemm_pipe<4, 4, 4, 2, false><<<dim3(8, 8, B_), 512, 0, stream>>>(
      P, Vt, out, 1024, 2048, 2048, 2048, 1024,
      (long)S_ * S_, (long)S_ * D_, (long)S_ * D_, 1.0f);
}

// Round 3
// 198.004 us; speedup vs baseline: 1.3017x; 1.0516x over previous
//
#include <hip/hip_runtime.h>
#include <stdint.h>

#define B_ 4
#define S_ 2048
#define D_ 1024

typedef __attribute__((ext_vector_type(8))) short short8;
typedef __attribute__((ext_vector_type(4))) float f32x4;

__device__ inline ushort f2bf(float f) {
  union { float f; uint32_t u; } v; v.f = f;
  uint32_t u = v.u;
  u += 0x7FFFu + ((u >> 16) & 1u);   // RNE
  return (ushort)(u >> 16);
}

__device__ inline void gload_lds16(const ushort* g, ushort* l) {
  __builtin_amdgcn_global_load_lds(
      (__attribute__((address_space(1))) void*)(uintptr_t)g,
      (__attribute__((address_space(3))) void*)(uintptr_t)l,
      16, 0, 0);
}

__device__ inline void vwaitN(int n) {
  switch (n) {
    case 0: asm volatile("s_waitcnt vmcnt(0)" ::: "memory"); break;
    case 1: asm volatile("s_waitcnt vmcnt(1)" ::: "memory"); break;
    case 2: asm volatile("s_waitcnt vmcnt(2)" ::: "memory"); break;
    case 6: asm volatile("s_waitcnt vmcnt(6)" ::: "memory"); break;
    default: asm volatile("s_waitcnt vmcnt(8)" ::: "memory"); break;
  }
  __builtin_amdgcn_sched_barrier(0);
}

// ---------------- fp32 -> bf16 convert ----------------
__global__ __launch_bounds__(256) void convert_f32_bf16(
    const float* __restrict__ in, ushort* __restrict__ out, int n) {
  int i = (blockIdx.x * 256 + threadIdx.x) * 4;
  if (i >= n) return;
  float4 f = *(const float4*)(in + i);
  ushort4 o;
  o.x = f2bf(f.x); o.y = f2bf(f.y); o.z = f2bf(f.z); o.w = f2bf(f.w);
  *(ushort4*)(out + i) = o;
}

// ---- quadrant-phased NT GEMM, A 2-buf + B ring-3, counted vmcnt ----
// C[m][n] = scale * sum_k A[m][k]*B[n][k]; BK=64, 512 thr = 8 waves (2M x 4N).
// LDS rows = full 128B K-rows, chunk swizzle: LDS[r][c] = G[r][c ^ (r&7)].
// Phases per tile: (M-half, k-slice); B frags reused across M-halves.

template <int H, int KS, int BM, int BN, class STG>
__device__ inline void do_phase(
    const ushort* sa, const ushort* sb,
    short8 (&bf)[2][BN / 64], f32x4 (&acc)[BM / 32][BN / 64],
    int wr, int wc, int la, int kg, STG&& stg) {
  constexpr int MF = BM / 32, NF = BN / 64, J = MF / 2;
  const int cq = ((KS * 4 + kg) ^ (la & 7)) * 8;
  short8 af[J];
  #pragma unroll
  for (int j = 0; j < J; ++j) {
    int row = wr * (BM / 2) + H * (BM / 4) + j * 16 + la;
    af[j] = *(const short8*)&sa[row * 64 + cq];
  }
  if (H == 0) {
    #pragma unroll
    for (int nf = 0; nf < NF; ++nf) {
      int row = wc * (BN / 4) + nf * 16 + la;
      bf[KS][nf] = *(const short8*)&sb[row * 64 + cq];
    }
  }
  stg();
  __builtin_amdgcn_s_barrier();
  __builtin_amdgcn_s_setprio(1);
  #pragma unroll
  for (int j = 0; j < J; ++j)
    #pragma unroll
    for (int nf = 0; nf < NF; ++nf)
      acc[H * J + j][nf] = __builtin_amdgcn_mfma_f32_16x16x32_bf16(
          af[j], bf[KS][nf], acc[H * J + j][nf], 0, 0, 0);
  __builtin_amdgcn_s_setprio(0);
}

template <int BM, int BN, bool OUT_BF16>
__global__ __launch_bounds__(512, 2) void gemm_q(
    const ushort* __restrict__ A, const ushort* __restrict__ Bm,
    void* __restrict__ C, int N, int K, int lda, int ldb, int ldc,
    long sA, long sB, long sC, float scale) {
  constexpr int MF = BM / 32, NF = BN / 64;
  constexpr int LAH = BM / 128;        // gloads/thread per A half-unit
  constexpr int LBH = BN / 128;        // gloads/thread per B half-unit
  constexpr int W = 2 * LAH + 2 * LBH; // steady-state vmcnt
  constexpr int ABUF = BM * 64;        // ushorts per A buffer
  constexpr int BBUF = BN * 64;
  __shared__ ushort lds[2 * ABUF + 3 * BBUF];
  ushort* ldsA = lds;
  ushort* ldsB = lds + 2 * ABUF;

  const int tid = threadIdx.x;
  const int wid = tid >> 6, lane = tid & 63;
  const int wr = wid >> 2, wc = wid & 3;       // 2M x 4N waves
  const int la = lane & 15, kg = lane >> 4;
  const int m0 = blockIdx.x * BM, n0 = blockIdx.y * BN;
  const ushort* Ag = A + (size_t)blockIdx.z * sA;
  const ushort* Bg = Bm + (size_t)blockIdx.z * sB;

  // stage address precompute (pre-swizzled global source, linear LDS dest)
  uint aOff[2][LAH]; int aDst[2][LAH];
  #pragma unroll
  for (int h = 0; h < 2; ++h)
    #pragma unroll
    for (int l = 0; l < LAH; ++l) {
      int li = l * 512 + tid, ridx = li >> 3, c = li & 7;
      int row = (ridx < BM / 4) ? h * (BM / 4) + ridx
                                : (h + 2) * (BM / 4) + (ridx - BM / 4);
      int gc = c ^ (row & 7);
      aOff[h][l] = (uint)((m0 + row) * lda + gc * 8);
      aDst[h][l] = row * 64 + c * 8;
    }
  uint bOff[2][LBH]; int bDst[2][LBH];
  #pragma unroll
  for (int h = 0; h < 2; ++h)
    #pragma unroll
    for (int l = 0; l < LBH; ++l) {
      int li = l * 512 + tid, ridx = li >> 3, c = li & 7;
      int row = h * (BN / 2) + ridx;
      int gc = c ^ (row & 7);
      bOff[h][l] = (uint)((n0 + row) * ldb + gc * 8);
      bDst[h][l] = row * 64 + c * 8;
    }

  auto stageA = [&](int h, int buf, int t) {
    #pragma unroll
    for (int l = 0; l < LAH; ++l)
      gload_lds16(Ag + aOff[h][l] + (size_t)t * 64, ldsA + buf * ABUF + aDst[h][l]);
  };
  auto stageB = [&](int h, int slot, int t) {
    #pragma unroll
    for (int l = 0; l < LBH; ++l)
      gload_lds16(Bg + bOff[h][l] + (size_t)t * 64, ldsB + slot * BBUF + bDst[h][l]);
  };

  f32x4 acc[MF][NF];
  #pragma unroll
  for (int m = 0; m < MF; ++m)
    #pragma unroll
    for (int n = 0; n < NF; ++n) acc[m][n] = (f32x4)(0.f);
  short8 bf[2][NF];

  const int NT = K / 64;

  // prologue: prime tiles 0 and 1 (order matters for vmcnt accounting)
  stageA(0, 0, 0); stageB(0, 0, 0);   // SA1(0), SB1(0)
  stageB(1, 0, 0);                    // SB2(0)
  stageA(1, 0, 0);                    // SA2(0)
  stageA(0, 1, 1); stageB(0, 1, 1);   // SA1(1), SB1(1)
  stageB(1, 1, 1);                    // SB2(1)
  vwaitN(W);                          // SA1(0),SB1(0),SB2(0) landed
  __builtin_amdgcn_s_barrier();

  for (int t = 0; t < NT; ++t) {
    const ushort* sa = ldsA + (t & 1) * ABUF;
    const ushort* sb = ldsB + (t % 3) * BBUF;
    const int bufN = (t + 1) & 1;
    const int slotN2 = (t + 2) % 3;

    // ph1 (M0,k0): reads A.G1 k0 + B k0; stage SA2(t+1)
    do_phase<0, 0, BM, BN>(sa, sb, bf, acc, wr, wc, la, kg,
        [&] { if (t + 1 < NT) stageA(1, bufN, t + 1); });
    __builtin_amdgcn_s_barrier();

    // ph2 (M0,k1): reads A.G1 k1 + B k1
    do_phase<0, 1, BM, BN>(sa, sb, bf, acc, wr, wc, la, kg, [&] {});
    vwaitN(t + 1 < NT ? W : 0);       // guards SA2(t) for ph3
    __builtin_amdgcn_s_barrier();

    // ph3 (M1,k0): reads A.G2 k0, B regs reused; stage SA1(t+2), SB1(t+2)
    do_phase<1, 0, BM, BN>(sa, sb, bf, acc, wr, wc, la, kg,
        [&] { if (t + 2 < NT) { stageA(0, t & 1, t + 2); stageB(0, slotN2, t + 2); } });
    __builtin_amdgcn_s_barrier();

    // ph4 (M1,k1); stage SB2(t+2)
    do_phase<1, 1, BM, BN>(sa, sb, bf, acc, wr, wc, la, kg,
        [&] { if (t + 2 < NT) stageB(1, slotN2, t + 2); });
    vwaitN(t + 2 < NT ? W : (t + 1 < NT ? LAH : 0));  // guards tile t+1 units
    __builtin_amdgcn_s_barrier();
  }

  // epilogue: C/D layout col=lane&15, row=(lane>>4)*4+jj
  char* Cb = (char*)C;
  #pragma unroll
  for (int m = 0; m < MF; ++m) {
    #pragma unroll
    for (int n = 0; n < NF; ++n) {
      int r = m0 + wr * (BM / 2) + m * 16 + kg * 4;
      int col = n0 + wc * (BN / 4) + n * 16 + la;
      #pragma unroll
      for (int jj = 0; jj < 4; ++jj) {
        float v = acc[m][n][jj] * scale;
        size_t idx = (size_t)blockIdx.z * sC + (size_t)(r + jj) * ldc + col;
        if (OUT_BF16) ((ushort*)Cb)[idx] = f2bf(v);
        else          ((float*)Cb)[idx]  = v;
      }
    }
  }
}

// ---------------- transpose V view [s][e] (ld 3072) -> Vt[b][e][s] ---------
__global__ void transpose_bf16(const ushort* __restrict__ qkv, ushort* __restrict__ out) {
  __shared__ ushort tile[32][33];
  int b = blockIdx.z;
  const ushort* src = qkv + (size_t)b * S_ * 3072 + 2048;  // V columns
  ushort* dst = out + (size_t)b * S_ * D_;
  int r0 = blockIdx.y * 32;   // S
  int c0 = blockIdx.x * 32;   // D
  int tx = threadIdx.x, ty = threadIdx.y;  // 32 x 8
  #pragma unroll
  for (int i = 0; i < 32; i += 8)
    tile[ty + i][tx] = src[(size_t)(r0 + ty + i) * 3072 + c0 + tx];
  __syncthreads();
  #pragma unroll
  for (int i = 0; i < 32; i += 8)
    dst[(size_t)(c0 + ty + i) * S_ + r0 + tx] = tile[tx][ty + i];
}

// ---------------- row softmax: fp32 scores -> bf16 probs ----------------
__global__ __launch_bounds__(256) void softmax_rows(
    const float* __restrict__ Sc, ushort* __restrict__ P) {
  size_t row = blockIdx.x;
  const float* src = Sc + row * S_;
  ushort* dst = P + row * S_;
  int tid = threadIdx.x;
  float vals[8];
  float m = -1e30f;
  #pragma unroll
  for (int i = 0; i < 8; ++i) {
    vals[i] = src[tid + i * 256];
    m = fmaxf(m, vals[i]);
  }
  #pragma unroll
  for (int off = 1; off < 64; off <<= 1) m = fmaxf(m, __shfl_xor(m, off));
  __shared__ float redm[4];
  if ((tid & 63) == 0) redm[tid >> 6] = m;
  __syncthreads();
  m = fmaxf(fmaxf(redm[0], redm[1]), fmaxf(redm[2], redm[3]));
  float s = 0.f;
  #pragma unroll
  for (int i = 0; i < 8; ++i) {
    vals[i] = __expf(vals[i] - m);
    s += vals[i];
  }
  #pragma unroll
  for (int off = 1; off < 64; off <<= 1) s += __shfl_xor(s, off);
  __shared__ float reds[4];
  if ((tid & 63) == 0) reds[tid >> 6] = s;
  __syncthreads();
  s = reds[0] + reds[1] + reds[2] + reds[3];
  float inv = 1.0f / s;
  #pragma unroll
  for (int i = 0; i < 8; ++i) dst[tid + i * 256] = f2bf(vals[i] * inv);
}

extern "C" void kernel_launch(void* const* d_in, const int* in_sizes, int n_in,
                              void* d_out, int out_size, void* d_ws, size_t ws_size,
                              hipStream_t stream) {
  const float* x  = (const float*)d_in[0];
  const float* Wq = (const float*)d_in[1];
  const float* Wk = (const float*)d_in[2];
  const float* Wv = (const float*)d_in[3];
  float* out = (float*)d_out;

  char* ws = (char*)d_ws;
  ushort* Xb   = (ushort*)(ws + 0);               // [8192][1024]
  ushort* Wcat = (ushort*)(ws + 16777216);        // [3072][1024]
  ushort* QKV  = (ushort*)(ws + 23068672);        // [8192][3072]
  ushort* Vt   = (ushort*)(ws + 73400320);        // [b][1024][2048]
  float*  Sc   = (float*) (ws + 90177536);        // [b][2048][2048] fp32
  ushort* P    = (ushort*)(ws + 157286400);       // [b][2048][2048] bf16

  const int NX = B_ * S_ * D_;   // 8388608
  const int NW = D_ * D_;        // 1048576

  convert_f32_bf16<<<NX / 4 / 256, 256, 0, stream>>>(x, Xb, NX);
  convert_f32_bf16<<<NW / 4 / 256, 256, 0, stream>>>(Wq, Wcat, NW);
  convert_f32_bf16<<<NW / 4 / 256, 256, 0, stream>>>(Wk, Wcat + (size_t)D_ * D_, NW);
  convert_f32_bf16<<<NW / 4 / 256, 256, 0, stream>>>(Wv, Wcat + (size_t)2 * D_ * D_, NW);

  // fused QKV projection: M=8192, N=3072, K=1024 (128x256, grid 64x12=768)
  gemm_q<128, 256, true><<<dim3(64, 12, 1), 512, 0, stream>>>(
      Xb, Wcat, QKV, 3072, 1024, 1024, 1024, 3072, 0, 0, 0, 1.0f);

  transpose_bf16<<<dim3(D_ / 32, S_ / 32, B_), dim3(32, 8), 0, stream>>>(QKV, Vt);

  // scores: per batch M=N=2048, K=1024 (256x256, grid 8x8x4=256)
  gemm_q<256, 256, false><<<dim3(8, 8, B_), 512, 0, stream>>>(
      QKV, QKV + 1024, Sc, 2048, 1024, 3072, 3072, 2048,
      (long)S_ * 3072, (long)S_ * 3072, (long)S_ * S_, 1.0f / 32.0f);

  softmax_rows<<<B_ * S_, 256, 0, stream>>>(Sc, P);

  // out = P @ Vt^T: per batch M=2048, N=1024, K=2048 (128x256, grid 16x4x4=256)
  gemm_q<128, 256, false><<<dim3(16, 4, B_), 512, 0, stream>>>(
      P, Vt, out, 1024, 2048, 2048, 2048, 1024,
      (long)S_ * S_, (long)S_ * D_, (long)S_ * D_, 1.0f);
}

// Round 4
// 197.602 us; speedup vs baseline: 1.3043x; 1.0020x over previous
//
#include <hip/hip_runtime.h>
#include <stdint.h>

#define B_ 4
#define S_ 2048
#define D_ 1024

typedef __attribute__((ext_vector_type(8))) short short8;
typedef __attribute__((ext_vector_type(4))) float f32x4;

__device__ inline ushort f2bf(float f) {
  union { float f; uint32_t u; } v; v.f = f;
  uint32_t u = v.u;
  u += 0x7FFFu + ((u >> 16) & 1u);   // RNE
  return (ushort)(u >> 16);
}

__device__ inline void gload_lds16(const ushort* g, ushort* l) {
  __builtin_amdgcn_global_load_lds(
      (__attribute__((address_space(1))) void*)(uintptr_t)g,
      (__attribute__((address_space(3))) void*)(uintptr_t)l,
      16, 0, 0);
}

__device__ inline void vwaitN(int n) {
  switch (n) {
    case 0: asm volatile("s_waitcnt vmcnt(0)" ::: "memory"); break;
    case 1: asm volatile("s_waitcnt vmcnt(1)" ::: "memory"); break;
    case 2: asm volatile("s_waitcnt vmcnt(2)" ::: "memory"); break;
    case 3: asm volatile("s_waitcnt vmcnt(3)" ::: "memory"); break;
    case 4: asm volatile("s_waitcnt vmcnt(4)" ::: "memory"); break;
    case 5: asm volatile("s_waitcnt vmcnt(5)" ::: "memory"); break;
    case 6: asm volatile("s_waitcnt vmcnt(6)" ::: "memory"); break;
    default: asm volatile("s_waitcnt vmcnt(8)" ::: "memory"); break;
  }
  __builtin_amdgcn_sched_barrier(0);
}

__device__ inline void sbar() {
  __builtin_amdgcn_s_barrier();
  __builtin_amdgcn_sched_barrier(0);
}

// ---------------- fp32 -> bf16 convert ----------------
__global__ __launch_bounds__(256) void convert_f32_bf16(
    const float* __restrict__ in, ushort* __restrict__ out, int n) {
  int i = (blockIdx.x * 256 + threadIdx.x) * 4;
  if (i >= n) return;
  float4 f = *(const float4*)(in + i);
  ushort4 o;
  o.x = f2bf(f.x); o.y = f2bf(f.y); o.z = f2bf(f.z); o.w = f2bf(f.w);
  *(ushort4*)(out + i) = o;
}

// ---- reg-pipelined quadrant NT GEMM, A 2-buf + B ring-3, counted vmcnt ----
// C[m][n] = scale * sum_k A[m][k]*B[n][k]; BK=64, 512 thr = 8 waves (2M x 4N).
// Phases per tile: (H=M-half, KS=k-slice). Fragments for phase p+1 are
// ds_read during phase p so the MFMA burst hides LDS latency.
// Swizzle: LDS[r][c] = G[r][c ^ (r&7)] (16B chunks); reads XOR the same key.

template <int H, int BM, int BN>
__device__ inline void mfma_ph(short8 (&afv)[BM / 64], short8 (&bfv)[BN / 64],
                               f32x4 (&acc)[BM / 32][BN / 64]) {
  constexpr int J = BM / 64, NF = BN / 64;
  __builtin_amdgcn_s_setprio(1);
  #pragma unroll
  for (int j = 0; j < J; ++j)
    #pragma unroll
    for (int nf = 0; nf < NF; ++nf)
      acc[H * J + j][nf] = __builtin_amdgcn_mfma_f32_16x16x32_bf16(
          afv[j], bfv[nf], acc[H * J + j][nf], 0, 0, 0);
  __builtin_amdgcn_s_setprio(0);
}

template <int BM, int BN, bool OUT_BF16>
__global__ __launch_bounds__(512, 2) void gemm_p(
    const ushort* __restrict__ A, const ushort* __restrict__ Bm,
    void* __restrict__ C, int N, int K, int lda, int ldb, int ldc,
    long sA, long sB, long sC, float scale) {
  constexpr int J = BM / 64, NF = BN / 64, MF = BM / 32;
  constexpr int LAH = BM / 128;        // gloads/thread per A half-unit
  constexpr int LBH = BN / 128;        // gloads/thread per B half-unit
  constexpr int ABUF = BM * 64;        // ushorts per A buffer
  constexpr int BBUF = BN * 64;
  constexpr int VW1 = 2 * LAH + 2 * LBH;
  constexpr int VW3F = 2 * LAH + LBH;  // full vw3
  constexpr int VWP = LAH + 2 * LBH;   // prologue
  __shared__ ushort lds[2 * ABUF + 3 * BBUF];
  ushort* ldsA = lds;
  ushort* ldsB = lds + 2 * ABUF;

  // XCD-aware bijective block swizzle (grids are multiples of 8)
  int gx = gridDim.x, gy = gridDim.y;
  int nwg = gx * gy * gridDim.z;
  int lin = blockIdx.x + gx * (blockIdx.y + gy * blockIdx.z);
  int cpx = nwg >> 3;
  int swz = (lin & 7) * cpx + (lin >> 3);
  int bx = swz % gx, by = (swz / gx) % gy, bz = swz / (gx * gy);

  const int tid = threadIdx.x;
  const int wid = tid >> 6, lane = tid & 63;
  const int wr = wid >> 2, wc = wid & 3;       // 2M x 4N waves
  const int la = lane & 15, kg = lane >> 4;
  const int m0 = bx * BM, n0 = by * BN;
  const ushort* Ag = A + (size_t)bz * sA;
  const ushort* Bg = Bm + (size_t)bz * sB;

  // stage address precompute (pre-swizzled global source, linear LDS dest)
  uint aOff[2][LAH]; int aDst[2][LAH];
  #pragma unroll
  for (int h = 0; h < 2; ++h)
    #pragma unroll
    for (int l = 0; l < LAH; ++l) {
      int li = l * 512 + tid, ridx = li >> 3, c = li & 7;
      int row = (ridx < BM / 4) ? h * (BM / 4) + ridx
                                : (h + 2) * (BM / 4) + (ridx - BM / 4);
      int gc = c ^ (row & 7);
      aOff[h][l] = (uint)((m0 + row) * lda + gc * 8);
      aDst[h][l] = row * 64 + c * 8;
    }
  uint bOff[2][LBH]; int bDst[2][LBH];
  #pragma unroll
  for (int h = 0; h < 2; ++h)
    #pragma unroll
    for (int l = 0; l < LBH; ++l) {
      int li = l * 512 + tid, ridx = li >> 3, c = li & 7;
      int row = h * (BN / 2) + ridx;
      int gc = c ^ (row & 7);
      bOff[h][l] = (uint)((n0 + row) * ldb + gc * 8);
      bDst[h][l] = row * 64 + c * 8;
    }

  auto stageA = [&](int h, int buf, int t) {
    #pragma unroll
    for (int l = 0; l < LAH; ++l)
      gload_lds16(Ag + aOff[h][l] + (size_t)t * 64, ldsA + buf * ABUF + aDst[h][l]);
  };
  auto stageB = [&](int h, int slot, int t) {
    #pragma unroll
    for (int l = 0; l < LBH; ++l)
      gload_lds16(Bg + bOff[h][l] + (size_t)t * 64, ldsB + slot * BBUF + bDst[h][l]);
  };

  // fragment readers: read frags of (tile-buf base, H, k-slice KS)
  auto rdA = [&](short8 (&dst)[J], const ushort* base, int H, int KS) {
    #pragma unroll
    for (int j = 0; j < J; ++j) {
      int row = wr * (BM / 2) + H * (BM / 4) + j * 16 + la;
      int kc = ((KS * 4 + kg) ^ (row & 7)) * 8;
      dst[j] = *(const short8*)&base[row * 64 + kc];
    }
  };
  auto rdB = [&](short8 (&dst)[NF], const ushort* base, int KS) {
    #pragma unroll
    for (int nf = 0; nf < NF; ++nf) {
      int row = wc * 64 + nf * 16 + la;
      int kc = ((KS * 4 + kg) ^ (row & 7)) * 8;
      dst[nf] = *(const short8*)&base[row * 64 + kc];
    }
  };

  f32x4 acc[MF][NF];
  #pragma unroll
  for (int m = 0; m < MF; ++m)
    #pragma unroll
    for (int n = 0; n < NF; ++n) acc[m][n] = (f32x4)(0.f);
  short8 af0[J], af1[J], bf0[NF], bf1[NF];

  const int NT = K / 64;

  // prologue stages (queue order matters for vmcnt accounting)
  stageA(0, 0, 0); stageB(0, 0, 0); stageB(1, 0, 0);  // SA1(0),SB1(0),SB2(0)
  stageA(1, 0, 0);                                     // SA2(0)
  stageA(0, 1, 1); stageB(0, 1, 1); stageB(1, 1, 1);  // SA1(1),SB1(1),SB2(1)
  vwaitN(VWP);                       // tile-0 units landed
  sbar();
  rdA(af0, ldsA, 0, 0);              // (t0,H0,K0)
  rdB(bf0, ldsB, 0);                 // (t0,K0)

  for (int t = 0; t < NT; ++t) {
    const ushort* sa = ldsA + (t & 1) * ABUF;
    const ushort* sb = ldsB + (t % 3) * BBUF;
    const ushort* saN = ldsA + ((t + 1) & 1) * ABUF;
    const ushort* sbN = ldsB + ((t + 1) % 3) * BBUF;
    const int slotN2 = (t + 2) % 3;

    // p0 (H0,K0): reads af1<-(t,H0,K1), bf1<-(t,K1); stage SA2(t+1)
    sbar();
    rdA(af1, sa, 0, 1);
    rdB(bf1, sb, 1);
    if (t + 1 < NT) stageA(1, (t + 1) & 1, t + 1);
    mfma_ph<0, BM, BN>(af0, bf0, acc);

    // p1 (H0,K1): reads af0<-(t,H1,K0)  [needs SA2(t)]
    vwaitN(t + 1 < NT ? VW1 : 0);
    sbar();
    rdA(af0, sa, 1, 0);
    mfma_ph<0, BM, BN>(af1, bf1, acc);

    // p2 (H1,K0): reads af1<-(t,H1,K1); stage SA1(t+2), SB1(t+2)
    sbar();
    rdA(af1, sa, 1, 1);
    if (t + 2 < NT) { stageA(0, (t + 2) & 1, t + 2); stageB(0, slotN2, t + 2); }
    mfma_ph<1, BM, BN>(af0, bf0, acc);

    // p3 (H1,K1): reads af0<-(t+1,H0,K0), bf0<-(t+1,K0); stage SB2(t+2)
    vwaitN(t + 1 < NT ? (t + 2 < NT ? VW3F : LAH) : 0);
    sbar();
    rdA(af0, saN, 0, 0);
    rdB(bf0, sbN, 0);
    if (t + 2 < NT) stageB(1, slotN2, t + 2);
    mfma_ph<1, BM, BN>(af1, bf1, acc);
  }

  // epilogue: C/D layout col=lane&15, row=(lane>>4)*4+jj
  char* Cb = (char*)C;
  #pragma unroll
  for (int m = 0; m < MF; ++m) {
    #pragma unroll
    for (int n = 0; n < NF; ++n) {
      int r = m0 + wr * (BM / 2) + m * 16 + kg * 4;
      int col = n0 + wc * 64 + n * 16 + la;
      #pragma unroll
      for (int jj = 0; jj < 4; ++jj) {
        float v = acc[m][n][jj] * scale;
        size_t idx = (size_t)bz * sC + (size_t)(r + jj) * ldc + col;
        if (OUT_BF16) ((ushort*)Cb)[idx] = f2bf(v);
        else          ((float*)Cb)[idx]  = v;
      }
    }
  }
}

// ---------------- transpose V view [s][e] (ld 3072) -> Vt[b][e][s] ---------
__global__ void transpose_bf16(const ushort* __restrict__ qkv, ushort* __restrict__ out) {
  __shared__ ushort tile[32][33];
  int b = blockIdx.z;
  const ushort* src = qkv + (size_t)b * S_ * 3072 + 2048;  // V columns
  ushort* dst = out + (size_t)b * S_ * D_;
  int r0 = blockIdx.y * 32;   // S
  int c0 = blockIdx.x * 32;   // D
  int tx = threadIdx.x, ty = threadIdx.y;  // 32 x 8
  #pragma unroll
  for (int i = 0; i < 32; i += 8)
    tile[ty + i][tx] = src[(size_t)(r0 + ty + i) * 3072 + c0 + tx];
  __syncthreads();
  #pragma unroll
  for (int i = 0; i < 32; i += 8)
    dst[(size_t)(c0 + ty + i) * S_ + r0 + tx] = tile[tx][ty + i];
}

// ---------------- row softmax: fp32 scores -> bf16 probs ----------------
__global__ __launch_bounds__(256) void softmax_rows(
    const float* __restrict__ Sc, ushort* __restrict__ P) {
  size_t row = blockIdx.x;
  const float* src = Sc + row * S_;
  ushort* dst = P + row * S_;
  int tid = threadIdx.x;
  float vals[8];
  float m = -1e30f;
  #pragma unroll
  for (int i = 0; i < 8; ++i) {
    vals[i] = src[tid + i * 256];
    m = fmaxf(m, vals[i]);
  }
  #pragma unroll
  for (int off = 1; off < 64; off <<= 1) m = fmaxf(m, __shfl_xor(m, off));
  __shared__ float redm[4];
  if ((tid & 63) == 0) redm[tid >> 6] = m;
  __syncthreads();
  m = fmaxf(fmaxf(redm[0], redm[1]), fmaxf(redm[2], redm[3]));
  float s = 0.f;
  #pragma unroll
  for (int i = 0; i < 8; ++i) {
    vals[i] = __expf(vals[i] - m);
    s += vals[i];
  }
  #pragma unroll
  for (int off = 1; off < 64; off <<= 1) s += __shfl_xor(s, off);
  __shared__ float reds[4];
  if ((tid & 63) == 0) reds[tid >> 6] = s;
  __syncthreads();
  s = reds[0] + reds[1] + reds[2] + reds[3];
  float inv = 1.0f / s;
  #pragma unroll
  for (int i = 0; i < 8; ++i) dst[tid + i * 256] = f2bf(vals[i] * inv);
}

extern "C" void kernel_launch(void* const* d_in, const int* in_sizes, int n_in,
                              void* d_out, int out_size, void* d_ws, size_t ws_size,
                              hipStream_t stream) {
  const float* x  = (const float*)d_in[0];
  const float* Wq = (const float*)d_in[1];
  const float* Wk = (const float*)d_in[2];
  const float* Wv = (const float*)d_in[3];
  float* out = (float*)d_out;

  char* ws = (char*)d_ws;
  ushort* Xb   = (ushort*)(ws + 0);               // [8192][1024]
  ushort* Wcat = (ushort*)(ws + 16777216);        // [3072][1024]
  ushort* QKV  = (ushort*)(ws + 23068672);        // [8192][3072]
  ushort* Vt   = (ushort*)(ws + 73400320);        // [b][1024][2048]
  float*  Sc   = (float*) (ws + 90177536);        // [b][2048][2048] fp32
  ushort* P    = (ushort*)(ws + 157286400);       // [b][2048][2048] bf16

  const int NX = B_ * S_ * D_;   // 8388608
  const int NW = D_ * D_;        // 1048576

  convert_f32_bf16<<<NX / 4 / 256, 256, 0, stream>>>(x, Xb, NX);
  convert_f32_bf16<<<NW / 4 / 256, 256, 0, stream>>>(Wq, Wcat, NW);
  convert_f32_bf16<<<NW / 4 / 256, 256, 0, stream>>>(Wk, Wcat + (size_t)D_ * D_, NW);
  convert_f32_bf16<<<NW / 4 / 256, 256, 0, stream>>>(Wv, Wcat + (size_t)2 * D_ * D_, NW);

  // fused QKV projection: M=8192, N=3072, K=1024 (128x256, grid 64x12=768)
  gemm_p<128, 256, true><<<dim3(64, 12, 1), 512, 0, stream>>>(
      Xb, Wcat, QKV, 3072, 1024, 1024, 1024, 3072, 0, 0, 0, 1.0f);

  transpose_bf16<<<dim3(D_ / 32, S_ / 32, B_), dim3(32, 8), 0, stream>>>(QKV, Vt);

  // scores: per batch M=N=2048, K=1024 (256x256, grid 8x8x4=256)
  gemm_p<256, 256, false><<<dim3(8, 8, B_), 512, 0, stream>>>(
      QKV, QKV + 1024, Sc, 2048, 1024, 3072, 3072, 2048,
      (long)S_ * 3072, (long)S_ * 3072, (long)S_ * S_, 1.0f / 32.0f);

  softmax_rows<<<B_ * S_, 256, 0, stream>>>(Sc, P);

  // out = P @ Vt^T: per batch M=2048, N=1024, K=2048 (128x256, grid 16x4x4=256)
  gemm_p<128, 256, false><<<dim3(16, 4, B_), 512, 0, stream>>>(
      P, Vt, out, 1024, 2048, 2048, 2048, 1024,
      (long)S_ * S_, (long)S_ * D_, (long)S_ * D_, 1.0f);
}

// Round 5
// 187.214 us; speedup vs baseline: 1.3767x; 1.0555x over previous
//
#include <hip/hip_runtime.h>
#include <stdint.h>

#define B_ 4
#define S_ 2048
#define D_ 1024

typedef __attribute__((ext_vector_type(8))) short short8;
typedef __attribute__((ext_vector_type(4))) float f32x4;

__device__ inline ushort f2bf(float f) {
  union { float f; uint32_t u; } v; v.f = f;
  uint32_t u = v.u;
  u += 0x7FFFu + ((u >> 16) & 1u);   // RNE
  return (ushort)(u >> 16);
}

__device__ inline void gload_lds16(const ushort* g, ushort* l) {
  __builtin_amdgcn_global_load_lds(
      (__attribute__((address_space(1))) void*)(uintptr_t)g,
      (__attribute__((address_space(3))) void*)(uintptr_t)l,
      16, 0, 0);
}

// counted vmcnt wait — memory clobber only, NO sched_barrier (m141 lesson)
__device__ inline void vwaitN(int n) {
  switch (n) {
    case 0: asm volatile("s_waitcnt vmcnt(0)" ::: "memory"); break;
    case 1: asm volatile("s_waitcnt vmcnt(1)" ::: "memory"); break;
    case 2: asm volatile("s_waitcnt vmcnt(2)" ::: "memory"); break;
    case 3: asm volatile("s_waitcnt vmcnt(3)" ::: "memory"); break;
    case 4: asm volatile("s_waitcnt vmcnt(4)" ::: "memory"); break;
    case 5: asm volatile("s_waitcnt vmcnt(5)" ::: "memory"); break;
    case 6: asm volatile("s_waitcnt vmcnt(6)" ::: "memory"); break;
    default: asm volatile("s_waitcnt vmcnt(8)" ::: "memory"); break;
  }
}

__device__ inline void sbar() {
  asm volatile("s_barrier" ::: "memory");
}

// ---------------- fused fp32 -> bf16 convert (x + Wq|Wk|Wv) ----------------
__global__ __launch_bounds__(256) void convert_all(
    const float* __restrict__ x, const float* __restrict__ wq,
    const float* __restrict__ wk, const float* __restrict__ wv,
    ushort* __restrict__ xb, ushort* __restrict__ wcat) {
  const int NX = B_ * S_ * D_;
  const int NW = D_ * D_;
  int e = (blockIdx.x * 256 + threadIdx.x) * 4;
  const float* src;
  ushort* dst;
  if (e < NX) {
    src = x + e; dst = xb + e;
  } else {
    int e2 = e - NX;
    int w = e2 / NW, off = e2 - w * NW;
    src = (w == 0 ? wq : w == 1 ? wk : wv) + off;
    dst = wcat + e2;
  }
  float4 f = *(const float4*)src;
  ushort4 o;
  o.x = f2bf(f.x); o.y = f2bf(f.y); o.z = f2bf(f.z); o.w = f2bf(f.w);
  *(ushort4*)dst = o;
}

// ---- reg-pipelined quadrant NT GEMM, A 2-buf + B ring-3, counted vmcnt ----
// C[m][n] = scale * sum_k A[m][k]*B[n][k]; BK=64, 512 thr = 8 waves (2M x 4N).
// Fragments for phase p+1 are ds_read during phase p (MFMA hides LDS latency).
// Swizzle: LDS[r][c] = G[r][c ^ (r&7)] (16B chunks); reads XOR the same key.

template <int H, int BM, int BN>
__device__ inline void mfma_ph(short8 (&afv)[BM / 64], short8 (&bfv)[BN / 64],
                               f32x4 (&acc)[BM / 32][BN / 64]) {
  constexpr int J = BM / 64, NF = BN / 64;
  __builtin_amdgcn_s_setprio(1);
  #pragma unroll
  for (int j = 0; j < J; ++j)
    #pragma unroll
    for (int nf = 0; nf < NF; ++nf)
      acc[H * J + j][nf] = __builtin_amdgcn_mfma_f32_16x16x32_bf16(
          afv[j], bfv[nf], acc[H * J + j][nf], 0, 0, 0);
  __builtin_amdgcn_s_setprio(0);
}

template <int BM, int BN, bool OUT_BF16>
__global__ __launch_bounds__(512, 2) void gemm_p(
    const ushort* __restrict__ A, const ushort* __restrict__ Bm,
    void* __restrict__ C, int N, int K, int lda, int ldb, int ldc,
    long sA, long sB, long sC, float scale) {
  constexpr int J = BM / 64, NF = BN / 64, MF = BM / 32;
  constexpr int LAH = BM / 128;        // gloads/thread per A half-unit
  constexpr int LBH = BN / 128;        // gloads/thread per B half-unit
  constexpr int ABUF = BM * 64;        // ushorts per A buffer
  constexpr int BBUF = BN * 64;
  constexpr int VW1 = 2 * LAH + 2 * LBH;
  constexpr int VW3F = 2 * LAH + LBH;  // full vw3
  constexpr int VWP = LAH + 2 * LBH;   // prologue
  __shared__ ushort lds[2 * ABUF + 3 * BBUF];
  ushort* ldsA = lds;
  ushort* ldsB = lds + 2 * ABUF;

  const int tid = threadIdx.x;
  const int wid = tid >> 6, lane = tid & 63;
  const int wr = wid >> 2, wc = wid & 3;       // 2M x 4N waves
  const int la = lane & 15, kg = lane >> 4;
  const int m0 = blockIdx.x * BM, n0 = blockIdx.y * BN;
  const int bz = blockIdx.z;
  const ushort* Ag = A + (size_t)bz * sA;
  const ushort* Bg = Bm + (size_t)bz * sB;

  // stage address precompute (pre-swizzled global source, linear LDS dest)
  uint aOff[2][LAH]; int aDst[2][LAH];
  #pragma unroll
  for (int h = 0; h < 2; ++h)
    #pragma unroll
    for (int l = 0; l < LAH; ++l) {
      int li = l * 512 + tid, ridx = li >> 3, c = li & 7;
      int row = (ridx < BM / 4) ? h * (BM / 4) + ridx
                                : (h + 2) * (BM / 4) + (ridx - BM / 4);
      int gc = c ^ (row & 7);
      aOff[h][l] = (uint)((m0 + row) * lda + gc * 8);
      aDst[h][l] = row * 64 + c * 8;
    }
  uint bOff[2][LBH]; int bDst[2][LBH];
  #pragma unroll
  for (int h = 0; h < 2; ++h)
    #pragma unroll
    for (int l = 0; l < LBH; ++l) {
      int li = l * 512 + tid, ridx = li >> 3, c = li & 7;
      int row = h * (BN / 2) + ridx;
      int gc = c ^ (row & 7);
      bOff[h][l] = (uint)((n0 + row) * ldb + gc * 8);
      bDst[h][l] = row * 64 + c * 8;
    }

  auto stageA = [&](int h, int buf, int t) {
    #pragma unroll
    for (int l = 0; l < LAH; ++l)
      gload_lds16(Ag + aOff[h][l] + (size_t)t * 64, ldsA + buf * ABUF + aDst[h][l]);
  };
  auto stageB = [&](int h, int slot, int t) {
    #pragma unroll
    for (int l = 0; l < LBH; ++l)
      gload_lds16(Bg + bOff[h][l] + (size_t)t * 64, ldsB + slot * BBUF + bDst[h][l]);
  };

  // fragment readers: read frags of (tile-buf base, H, k-slice KS)
  auto rdA = [&](short8 (&dst)[J], const ushort* base, int H, int KS) {
    #pragma unroll
    for (int j = 0; j < J; ++j) {
      int row = wr * (BM / 2) + H * (BM / 4) + j * 16 + la;
      int kc = ((KS * 4 + kg) ^ (row & 7)) * 8;
      dst[j] = *(const short8*)&base[row * 64 + kc];
    }
  };
  auto rdB = [&](short8 (&dst)[NF], const ushort* base, int KS) {
    #pragma unroll
    for (int nf = 0; nf < NF; ++nf) {
      int row = wc * 64 + nf * 16 + la;
      int kc = ((KS * 4 + kg) ^ (row & 7)) * 8;
      dst[nf] = *(const short8*)&base[row * 64 + kc];
    }
  };

  f32x4 acc[MF][NF];
  #pragma unroll
  for (int m = 0; m < MF; ++m)
    #pragma unroll
    for (int n = 0; n < NF; ++n) acc[m][n] = (f32x4)(0.f);
  short8 af0[J], af1[J], bf0[NF], bf1[NF];

  const int NT = K / 64;

  // prologue stages (queue order matters for vmcnt accounting)
  stageA(0, 0, 0); stageB(0, 0, 0); stageB(1, 0, 0);  // SA1(0),SB1(0),SB2(0)
  stageA(1, 0, 0);                                     // SA2(0)
  stageA(0, 1, 1); stageB(0, 1, 1); stageB(1, 1, 1);  // SA1(1),SB1(1),SB2(1)
  vwaitN(VWP);                       // tile-0 units landed
  sbar();
  rdA(af0, ldsA, 0, 0);              // (t0,H0,K0)
  rdB(bf0, ldsB, 0);                 // (t0,K0)

  for (int t = 0; t < NT; ++t) {
    const ushort* sa = ldsA + (t & 1) * ABUF;
    const ushort* sb = ldsB + (t % 3) * BBUF;
    const ushort* saN = ldsA + ((t + 1) & 1) * ABUF;
    const ushort* sbN = ldsB + ((t + 1) % 3) * BBUF;
    const int slotN2 = (t + 2) % 3;

    // p0 (H0,K0): reads af1<-(t,H0,K1), bf1<-(t,K1); stage SA2(t+1)
    sbar();
    rdA(af1, sa, 0, 1);
    rdB(bf1, sb, 1);
    if (t + 1 < NT) stageA(1, (t + 1) & 1, t + 1);
    mfma_ph<0, BM, BN>(af0, bf0, acc);

    // p1 (H0,K1): reads af0<-(t,H1,K0)  [needs SA2(t)]
    vwaitN(t + 1 < NT ? VW1 : 0);
    sbar();
    rdA(af0, sa, 1, 0);
    mfma_ph<0, BM, BN>(af1, bf1, acc);

    // p2 (H1,K0): reads af1<-(t,H1,K1); stage SA1(t+2), SB1(t+2)
    sbar();
    rdA(af1, sa, 1, 1);
    if (t + 2 < NT) { stageA(0, (t + 2) & 1, t + 2); stageB(0, slotN2, t + 2); }
    mfma_ph<1, BM, BN>(af0, bf0, acc);

    // p3 (H1,K1): reads af0<-(t+1,H0,K0), bf0<-(t+1,K0); stage SB2(t+2)
    vwaitN(t + 1 < NT ? (t + 2 < NT ? VW3F : LAH) : 0);
    sbar();
    rdA(af0, saN, 0, 0);
    rdB(bf0, sbN, 0);
    if (t + 2 < NT) stageB(1, slotN2, t + 2);
    mfma_ph<1, BM, BN>(af1, bf1, acc);
  }

  // epilogue: C/D layout col=lane&15, row=(lane>>4)*4+jj
  char* Cb = (char*)C;
  #pragma unroll
  for (int m = 0; m < MF; ++m) {
    #pragma unroll
    for (int n = 0; n < NF; ++n) {
      int r = m0 + wr * (BM / 2) + m * 16 + kg * 4;
      int col = n0 + wc * 64 + n * 16 + la;
      #pragma unroll
      for (int jj = 0; jj < 4; ++jj) {
        float v = acc[m][n][jj] * scale;
        size_t idx = (size_t)bz * sC + (size_t)(r + jj) * ldc + col;
        if (OUT_BF16) ((ushort*)Cb)[idx] = f2bf(v);
        else          ((float*)Cb)[idx]  = v;
      }
    }
  }
}

// ---------------- transpose V view [s][e] (ld 3072) -> Vt[b][e][s] ---------
__global__ void transpose_bf16(const ushort* __restrict__ qkv, ushort* __restrict__ out) {
  __shared__ ushort tile[32][33];
  int b = blockIdx.z;
  const ushort* src = qkv + (size_t)b * S_ * 3072 + 2048;  // V columns
  ushort* dst = out + (size_t)b * S_ * D_;
  int r0 = blockIdx.y * 32;   // S
  int c0 = blockIdx.x * 32;   // D
  int tx = threadIdx.x, ty = threadIdx.y;  // 32 x 8
  #pragma unroll
  for (int i = 0; i < 32; i += 8)
    tile[ty + i][tx] = src[(size_t)(r0 + ty + i) * 3072 + c0 + tx];
  __syncthreads();
  #pragma unroll
  for (int i = 0; i < 32; i += 8)
    dst[(size_t)(c0 + ty + i) * S_ + r0 + tx] = tile[tx][ty + i];
}

// ---------------- row softmax: fp32 scores -> bf16 probs ----------------
__global__ __launch_bounds__(256) void softmax_rows(
    const float* __restrict__ Sc, ushort* __restrict__ P) {
  size_t row = blockIdx.x;
  const float* src = Sc + row * S_;
  ushort* dst = P + row * S_;
  int tid = threadIdx.x;
  float vals[8];
  float m = -1e30f;
  #pragma unroll
  for (int i = 0; i < 8; ++i) {
    vals[i] = src[tid + i * 256];
    m = fmaxf(m, vals[i]);
  }
  #pragma unroll
  for (int off = 1; off < 64; off <<= 1) m = fmaxf(m, __shfl_xor(m, off));
  __shared__ float redm[4];
  if ((tid & 63) == 0) redm[tid >> 6] = m;
  __syncthreads();
  m = fmaxf(fmaxf(redm[0], redm[1]), fmaxf(redm[2], redm[3]));
  float s = 0.f;
  #pragma unroll
  for (int i = 0; i < 8; ++i) {
    vals[i] = __expf(vals[i] - m);
    s += vals[i];
  }
  #pragma unroll
  for (int off = 1; off < 64; off <<= 1) s += __shfl_xor(s, off);
  __shared__ float reds[4];
  if ((tid & 63) == 0) reds[tid >> 6] = s;
  __syncthreads();
  s = reds[0] + reds[1] + reds[2] + reds[3];
  float inv = 1.0f / s;
  #pragma unroll
  for (int i = 0; i < 8; ++i) dst[tid + i * 256] = f2bf(vals[i] * inv);
}

extern "C" void kernel_launch(void* const* d_in, const int* in_sizes, int n_in,
                              void* d_out, int out_size, void* d_ws, size_t ws_size,
                              hipStream_t stream) {
  const float* x  = (const float*)d_in[0];
  const float* Wq = (const float*)d_in[1];
  const float* Wk = (const float*)d_in[2];
  const float* Wv = (const float*)d_in[3];
  float* out = (float*)d_out;

  char* ws = (char*)d_ws;
  ushort* Xb   = (ushort*)(ws + 0);               // [8192][1024]
  ushort* Wcat = (ushort*)(ws + 16777216);        // [3072][1024]
  ushort* QKV  = (ushort*)(ws + 23068672);        // [8192][3072]
  ushort* Vt   = (ushort*)(ws + 73400320);        // [b][1024][2048]
  float*  Sc   = (float*) (ws + 90177536);        // [b][2048][2048] fp32
  ushort* P    = (ushort*)(ws + 157286400);       // [b][2048][2048] bf16

  const int NTOT = B_ * S_ * D_ + 3 * D_ * D_;    // 11534336

  convert_all<<<NTOT / 4 / 256, 256, 0, stream>>>(x, Wq, Wk, Wv, Xb, Wcat);

  // fused QKV projection: M=8192, N=3072, K=1024 (128x256, grid 64x12=768)
  gemm_p<128, 256, true><<<dim3(64, 12, 1), 512, 0, stream>>>(
      Xb, Wcat, QKV, 3072, 1024, 1024, 1024, 3072, 0, 0, 0, 1.0f);

  transpose_bf16<<<dim3(D_ / 32, S_ / 32, B_), dim3(32, 8), 0, stream>>>(QKV, Vt);

  // scores: per batch M=N=2048, K=1024 (256x256, grid 8x8x4=256)
  gemm_p<256, 256, false><<<dim3(8, 8, B_), 512, 0, stream>>>(
      QKV, QKV + 1024, Sc, 2048, 1024, 3072, 3072, 2048,
      (long)S_ * 3072, (long)S_ * 3072, (long)S_ * S_, 1.0f / 32.0f);

  softmax_rows<<<B_ * S_, 256, 0, stream>>>(Sc, P);

  // out = P @ Vt^T: per batch M=2048, N=1024, K=2048 (128x256, grid 16x4x4=256)
  gemm_p<128, 256, false><<<dim3(16, 4, B_), 512, 0, stream>>>(
      P, Vt, out, 1024, 2048, 2048, 2048, 1024,
      (long)S_ * S_, (long)S_ * D_, (long)S_ * D_, 1.0f);
}

// Round 7
// 182.216 us; speedup vs baseline: 1.4145x; 1.0274x over previous
//
#include <hip/hip_runtime.h>
#include <stdint.h>

#define B_ 4
#define S_ 2048
#define D_ 1024

typedef __attribute__((ext_vector_type(8))) short short8;
typedef __attribute__((ext_vector_type(4))) float f32x4;
typedef __attribute__((ext_vector_type(4))) int int4v;

__device__ inline ushort f2bf(float f) {
  union { float f; uint32_t u; } v; v.f = f;
  uint32_t u = v.u;
  u += 0x7FFFu + ((u >> 16) & 1u);   // RNE
  return (ushort)(u >> 16);
}

__device__ inline void gload_lds16(const ushort* g, ushort* l) {
  __builtin_amdgcn_global_load_lds(
      (__attribute__((address_space(1))) void*)(uintptr_t)g,
      (__attribute__((address_space(3))) void*)(uintptr_t)l,
      16, 0, 0);
}

// LDS byte offset of a generic pointer into shared memory
__device__ inline uint lds_off(const ushort* p) {
  return (uint)(uintptr_t)(const __attribute__((address_space(3))) ushort*)(uintptr_t)p;
}

// opaque LDS read: compiler cannot see this as an LDS access, so it inserts
// no automatic waits; ordering vs our volatile-asm waits/barriers is fixed.
__device__ inline short8 dsr128(uint addr) {
  int4v r;
  asm volatile("ds_read_b128 %0, %1" : "=v"(r) : "v"(addr));
  return __builtin_bit_cast(short8, r);
}

__device__ inline void vwaitN(int n) {
  switch (n) {
    case 0: asm volatile("s_waitcnt vmcnt(0)"); break;
    case 1: asm volatile("s_waitcnt vmcnt(1)"); break;
    case 2: asm volatile("s_waitcnt vmcnt(2)"); break;
    case 6: asm volatile("s_waitcnt vmcnt(6)"); break;
    default: asm volatile("s_waitcnt vmcnt(8)"); break;
  }
}

__device__ inline void abar() { asm volatile("s_barrier"); }

__device__ inline void lgkm0() {
  asm volatile("s_waitcnt lgkmcnt(0)");
  __builtin_amdgcn_sched_barrier(0);   // rule #18: MFMA must not hoist above
}

// ---------------- fused fp32 -> bf16 convert (x + Wq|Wk|Wv) ----------------
__global__ __launch_bounds__(256) void convert_all(
    const float* __restrict__ x, const float* __restrict__ wq,
    const float* __restrict__ wk, const float* __restrict__ wv,
    ushort* __restrict__ xb, ushort* __restrict__ wcat) {
  const int NX = B_ * S_ * D_;
  const int NW = D_ * D_;
  int e = (blockIdx.x * 256 + threadIdx.x) * 4;
  const float* src;
  ushort* dst;
  if (e < NX) {
    src = x + e; dst = xb + e;
  } else {
    int e2 = e - NX;
    int w = e2 / NW, off = e2 - w * NW;
    src = (w == 0 ? wq : w == 1 ? wk : wv) + off;
    dst = wcat + e2;
  }
  float4 f = *(const float4*)src;
  ushort4 o;
  o.x = f2bf(f.x); o.y = f2bf(f.y); o.z = f2bf(f.z); o.w = f2bf(f.w);
  *(ushort4*)dst = o;
}

// ---- quadrant-phased NT GEMM, opaque asm ds_reads, counted vmcnt ----
// C[m][n] = scale * sum_k A[m][k]*B[n][k]; BK=64, 512 thr = 8 waves (2M x 4N).
// A double-buffered, B ring-3. Per K-tile 4 phases (H half x K slice):
//   p: [vwait][barrier] asm-ds_read frags ; stage ; lgkmcnt(0) ; MFMA
// Publish rule: reads of staged data always FOLLOW a vwait+barrier pair.
// Swizzle: LDS[r][c] = G[r][c ^ (r&7)] (16B chunks); reads XOR the same key.

template <int H, int BM, int BN>
__device__ inline void mfma_ph(short8 (&afv)[BM / 64], short8 (&bfv)[BN / 64],
                               f32x4 (&acc)[BM / 32][BN / 64]) {
  constexpr int J = BM / 64, NF = BN / 64;
  __builtin_amdgcn_s_setprio(1);
  #pragma unroll
  for (int j = 0; j < J; ++j)
    #pragma unroll
    for (int nf = 0; nf < NF; ++nf)
      acc[H * J + j][nf] = __builtin_amdgcn_mfma_f32_16x16x32_bf16(
          afv[j], bfv[nf], acc[H * J + j][nf], 0, 0, 0);
  __builtin_amdgcn_s_setprio(0);
}

template <int BM, int BN, bool OUT_BF16>
__global__ __launch_bounds__(512, 2) void gemm_p(
    const ushort* __restrict__ A, const ushort* __restrict__ Bm,
    void* __restrict__ C, int N, int K, int lda, int ldb, int ldc,
    long sA, long sB, long sC, float scale) {
  constexpr int J = BM / 64, NF = BN / 64, MF = BM / 32;
  constexpr int LAH = BM / 128;        // gloads/thread per A half-unit
  constexpr int LBH = BN / 128;        // gloads/thread per B half-unit
  constexpr int ABUF = BM * 64;        // ushorts per A buffer
  constexpr int BBUF = BN * 64;
  constexpr int VW1 = 2 * LAH + 2 * LBH;  // steady-state wait
  __shared__ ushort lds[2 * ABUF + 3 * BBUF];
  ushort* ldsA = lds;
  ushort* ldsB = lds + 2 * ABUF;

  const int tid = threadIdx.x;
  const int wid = tid >> 6, lane = tid & 63;
  const int wr = wid >> 2, wc = wid & 3;       // 2M x 4N waves
  const int la = lane & 15, kg = lane >> 4;
  const int m0 = blockIdx.x * BM, n0 = blockIdx.y * BN;
  const int bz = blockIdx.z;
  const ushort* Ag = A + (size_t)bz * sA;
  const ushort* Bg = Bm + (size_t)bz * sB;

  // stage address precompute (pre-swizzled global source, linear LDS dest)
  uint aOff[2][LAH]; int aDst[2][LAH];
  #pragma unroll
  for (int h = 0; h < 2; ++h)
    #pragma unroll
    for (int l = 0; l < LAH; ++l) {
      int li = l * 512 + tid, ridx = li >> 3, c = li & 7;
      int row = (ridx < BM / 4) ? h * (BM / 4) + ridx
                                : (h + 2) * (BM / 4) + (ridx - BM / 4);
      int gc = c ^ (row & 7);
      aOff[h][l] = (uint)((m0 + row) * lda + gc * 8);
      aDst[h][l] = row * 64 + c * 8;
    }
  uint bOff[2][LBH]; int bDst[2][LBH];
  #pragma unroll
  for (int h = 0; h < 2; ++h)
    #pragma unroll
    for (int l = 0; l < LBH; ++l) {
      int li = l * 512 + tid, ridx = li >> 3, c = li & 7;
      int row = h * (BN / 2) + ridx;
      int gc = c ^ (row & 7);
      bOff[h][l] = (uint)((n0 + row) * ldb + gc * 8);
      bDst[h][l] = row * 64 + c * 8;
    }

  auto stageA = [&](int h, int buf, int t) {
    #pragma unroll
    for (int l = 0; l < LAH; ++l)
      gload_lds16(Ag + aOff[h][l] + (size_t)t * 64, ldsA + buf * ABUF + aDst[h][l]);
  };
  auto stageB = [&](int h, int slot, int t) {
    #pragma unroll
    for (int l = 0; l < LBH; ++l)
      gload_lds16(Bg + bOff[h][l] + (size_t)t * 64, ldsB + slot * BBUF + bDst[h][l]);
  };

  // fragment LDS byte-offsets (per-thread constants)
  uint offA[2][2][J];
  #pragma unroll
  for (int h = 0; h < 2; ++h)
    #pragma unroll
    for (int ks = 0; ks < 2; ++ks)
      #pragma unroll
      for (int j = 0; j < J; ++j) {
        int row = wr * (BM / 2) + h * (BM / 4) + j * 16 + la;
        int kc = ((ks * 4 + kg) ^ (row & 7)) * 8;
        offA[h][ks][j] = (uint)((row * 64 + kc) * 2);
      }
  uint offB[2][NF];
  #pragma unroll
  for (int ks = 0; ks < 2; ++ks)
    #pragma unroll
    for (int nf = 0; nf < NF; ++nf) {
      int row = wc * 64 + nf * 16 + la;
      int kc = ((ks * 4 + kg) ^ (row & 7)) * 8;
      offB[ks][nf] = (uint)((row * 64 + kc) * 2);
    }
  const uint ldsA0 = lds_off(ldsA);
  const uint ldsB0 = lds_off(ldsB);

  f32x4 acc[MF][NF];
  #pragma unroll
  for (int m = 0; m < MF; ++m)
    #pragma unroll
    for (int n = 0; n < NF; ++n) acc[m][n] = (f32x4)(0.f);
  short8 af[J], bf0[NF], bf1[NF];

  const int NT = K / 64;

  // prologue: exact unit order for the vmcnt ledger
  stageA(0, 0, 0); stageB(0, 0, 0); stageB(1, 0, 0);  // A1(0),B1(0),B2(0)
  stageA(1, 0, 0);                                     // A2(0)
  stageA(0, 1, 1); stageB(0, 1, 1); stageB(1, 1, 1);  // A1(1),B1(1),B2(1)

  int bs = 0;                          // B ring slot of tile t
  for (int t = 0; t < NT; ++t) {
    const uint aB = ldsA0 + (uint)((t & 1) * ABUF * 2);
    const uint bB = ldsB0 + (uint)(bs * BBUF * 2);
    const int bs2 = (bs == 0) ? 2 : bs - 1;   // slot of tile t+2

    // p0 (H0,K0): publish tile-t A1/B1/B2; read af(H0K0)+bf0; stage A2(t+1)
    vwaitN(t + 1 < NT ? VW1 : LAH);
    abar();
    #pragma unroll
    for (int j = 0; j < J; ++j) af[j] = dsr128(aB + offA[0][0][j]);
    #pragma unroll
    for (int nf = 0; nf < NF; ++nf) bf0[nf] = dsr128(bB + offB[0][nf]);
    if (t + 1 < NT) stageA(1, (t + 1) & 1, t + 1);
    lgkm0();
    mfma_ph<0, BM, BN>(af, bf0, acc);

    // p1 (H0,K1): read af(H0K1)+bf1 (same buffers, already published)
    abar();
    #pragma unroll
    for (int j = 0; j < J; ++j) af[j] = dsr128(aB + offA[0][1][j]);
    #pragma unroll
    for (int nf = 0; nf < NF; ++nf) bf1[nf] = dsr128(bB + offB[1][nf]);
    lgkm0();
    mfma_ph<0, BM, BN>(af, bf1, acc);

    // p2 (H1,K0): publish A2(t); read af(H1K0); stage A1(t+2), B1(t+2)
    vwaitN(t + 1 < NT ? VW1 : 0);
    abar();
    #pragma unroll
    for (int j = 0; j < J; ++j) af[j] = dsr128(aB + offA[1][0][j]);
    if (t + 2 < NT) { stageA(0, t & 1, t + 2); stageB(0, bs2, t + 2); }
    lgkm0();
    mfma_ph<1, BM, BN>(af, bf0, acc);

    // p3 (H1,K1): read af(H1K1); stage B2(t+2)
    abar();
    #pragma unroll
    for (int j = 0; j < J; ++j) af[j] = dsr128(aB + offA[1][1][j]);
    if (t + 2 < NT) stageB(1, bs2, t + 2);
    lgkm0();
    mfma_ph<1, BM, BN>(af, bf1, acc);

    bs = (bs == 2) ? 0 : bs + 1;
  }

  // epilogue: C/D layout col=lane&15, row=(lane>>4)*4+jj
  char* Cb = (char*)C;
  #pragma unroll
  for (int m = 0; m < MF; ++m) {
    #pragma unroll
    for (int n = 0; n < NF; ++n) {
      int r = m0 + wr * (BM / 2) + m * 16 + kg * 4;
      int col = n0 + wc * 64 + n * 16 + la;
      #pragma unroll
      for (int jj = 0; jj < 4; ++jj) {
        float v = acc[m][n][jj] * scale;
        size_t idx = (size_t)bz * sC + (size_t)(r + jj) * ldc + col;
        if (OUT_BF16) ((ushort*)Cb)[idx] = f2bf(v);
        else          ((float*)Cb)[idx]  = v;
      }
    }
  }
}

// ---------------- transpose V view [s][e] (ld 3072) -> Vt[b][e][s] ---------
__global__ void transpose_bf16(const ushort* __restrict__ qkv, ushort* __restrict__ out) {
  __shared__ ushort tile[32][33];
  int b = blockIdx.z;
  const ushort* src = qkv + (size_t)b * S_ * 3072 + 2048;  // V columns
  ushort* dst = out + (size_t)b * S_ * D_;
  int r0 = blockIdx.y * 32;   // S
  int c0 = blockIdx.x * 32;   // D
  int tx = threadIdx.x, ty = threadIdx.y;  // 32 x 8
  #pragma unroll
  for (int i = 0; i < 32; i += 8)
    tile[ty + i][tx] = src[(size_t)(r0 + ty + i) * 3072 + c0 + tx];
  __syncthreads();
  #pragma unroll
  for (int i = 0; i < 32; i += 8)
    dst[(size_t)(c0 + ty + i) * S_ + r0 + tx] = tile[tx][ty + i];
}

// ---------------- row softmax: fp32 scores -> bf16 probs ----------------
__global__ __launch_bounds__(256) void softmax_rows(
    const float* __restrict__ Sc, ushort* __restrict__ P) {
  size_t row = blockIdx.x;
  const float* src = Sc + row * S_;
  ushort* dst = P + row * S_;
  int tid = threadIdx.x;
  float vals[8];
  float m = -1e30f;
  #pragma unroll
  for (int i = 0; i < 8; ++i) {
    vals[i] = src[tid + i * 256];
    m = fmaxf(m, vals[i]);
  }
  #pragma unroll
  for (int off = 1; off < 64; off <<= 1) m = fmaxf(m, __shfl_xor(m, off));
  __shared__ float redm[4];
  if ((tid & 63) == 0) redm[tid >> 6] = m;
  __syncthreads();
  m = fmaxf(fmaxf(redm[0], redm[1]), fmaxf(redm[2], redm[3]));
  float s = 0.f;
  #pragma unroll
  for (int i = 0; i < 8; ++i) {
    vals[i] = __expf(vals[i] - m);
    s += vals[i];
  }
  #pragma unroll
  for (int off = 1; off < 64; off <<= 1) s += __shfl_xor(s, off);
  __shared__ float reds[4];
  if ((tid & 63) == 0) reds[tid >> 6] = s;
  __syncthreads();
  s = reds[0] + reds[1] + reds[2] + reds[3];
  float inv = 1.0f / s;
  #pragma unroll
  for (int i = 0; i < 8; ++i) dst[tid + i * 256] = f2bf(vals[i] * inv);
}

extern "C" void kernel_launch(void* const* d_in, const int* in_sizes, int n_in,
                              void* d_out, int out_size, void* d_ws, size_t ws_size,
                              hipStream_t stream) {
  const float* x  = (const float*)d_in[0];
  const float* Wq = (const float*)d_in[1];
  const float* Wk = (const float*)d_in[2];
  const float* Wv = (const float*)d_in[3];
  float* out = (float*)d_out;

  char* ws = (char*)d_ws;
  ushort* Xb   = (ushort*)(ws + 0);               // [8192][1024]
  ushort* Wcat = (ushort*)(ws + 16777216);        // [3072][1024]
  ushort* QKV  = (ushort*)(ws + 23068672);        // [8192][3072]
  ushort* Vt   = (ushort*)(ws + 73400320);        // [b][1024][2048]
  float*  Sc   = (float*) (ws + 90177536);        // [b][2048][2048] fp32
  ushort* P    = (ushort*)(ws + 157286400);       // [b][2048][2048] bf16

  const int NTOT = B_ * S_ * D_ + 3 * D_ * D_;    // 11534336

  convert_all<<<NTOT / 4 / 256, 256, 0, stream>>>(x, Wq, Wk, Wv, Xb, Wcat);

  // fused QKV projection: M=8192, N=3072, K=1024 (128x256, grid 64x12=768)
  gemm_p<128, 256, true><<<dim3(64, 12, 1), 512, 0, stream>>>(
      Xb, Wcat, QKV, 3072, 1024, 1024, 1024, 3072, 0, 0, 0, 1.0f);

  transpose_bf16<<<dim3(D_ / 32, S_ / 32, B_), dim3(32, 8), 0, stream>>>(QKV, Vt);

  // scores: per batch M=N=2048, K=1024 (256x256, grid 8x8x4=256)
  gemm_p<256, 256, false><<<dim3(8, 8, B_), 512, 0, stream>>>(
      QKV, QKV + 1024, Sc, 2048, 1024, 3072, 3072, 2048,
      (long)S_ * 3072, (long)S_ * 3072, (long)S_ * S_, 1.0f / 32.0f);

  softmax_rows<<<B_ * S_, 256, 0, stream>>>(Sc, P);

  // out = P @ Vt^T: per batch M=2048, N=1024, K=2048 (128x256, grid 16x4x4=256)
  gemm_p<128, 256, false><<<dim3(16, 4, B_), 512, 0, stream>>>(
      P, Vt, out, 1024, 2048, 2048, 2048, 1024,
      (long)S_ * S_, (long)S_ * D_, (long)S_ * D_, 1.0f);
}